// Round 1
// baseline (75.660 us; speedup 1.0000x reference)
//
#include <hip/hip_runtime.h>
#include <math.h>

#define N_ELEC   1024
#define OUT_H    256
#define OUT_W    256
#define I_SCALE_C  8e-05f
#define RHEO_C     2.39e-05f
#define PW_C       0.00017f
#define FREQ_C     300.0f
#define SLOPE_C    19152642.5f
#define HALF_C     1.057e-07f
#define SPREAD_C   0.000675f
#define R2S_C      0.5f
#define LOG2E_C    1.4426950408889634f

typedef __attribute__((ext_vector_type(8))) short short8;
typedef __attribute__((ext_vector_type(4))) short short4v;
typedef __attribute__((ext_vector_type(4))) float float4v;

__device__ __forceinline__ float fast_exp2(float x) {
#if __has_builtin(__builtin_amdgcn_exp2f)
    return __builtin_amdgcn_exp2f(x);
#else
    return exp2f(x);
#endif
}

__device__ __forceinline__ unsigned short f2bf(float f) {
    unsigned int u = __float_as_uint(f);
    unsigned int r = (u + 0x7fffu + ((u >> 16) & 1u)) >> 16;
    return (unsigned short)r;
}

// ---------------------------------------------------------------------------
// Kernel 1: 2048 per-(batch,electrode) param sets -> ws  (was recomputed by
// all 512 tile-blocks = 512x redundant).
// prm = (c, vx_px, vy_px, log2Bw)
// ---------------------------------------------------------------------------
__global__ __launch_bounds__(256) void param_kernel(
    const float* __restrict__ stim, const float* __restrict__ vx,
    const float* __restrict__ vy,   const float* __restrict__ M,
    const float* __restrict__ px,   const int* __restrict__ idx,
    float4* __restrict__ prm_g)
{
    int gid = blockIdx.x * 256 + threadIdx.x;   // 0..2047
    int b = gid >> 10;
    int n = gid & (N_ELEC - 1);

    float fov = px[OUT_W - 1];
    float d2p = (float)OUT_W / (2.0f * fov);

    int   j    = idx[n];
    float I    = stim[b * N_ELEC + j] * I_SCALE_C;
    float Ieff = fmaxf(I - RHEO_C, 0.0f);
    float Q    = Ieff * (PW_C * FREQ_C);
    float s    = SLOPE_C * (Q - HALF_C);
    float Bw   = 1.0f / (1.0f + __expf(-s));
    float size_base = sqrtf(I / SPREAD_C);
    float sigma_px  = fmaxf(size_base * (R2S_C / M[n]) * d2p, 1.0f);
    float c    = -LOG2E_C / (2.0f * sigma_px * sigma_px);
    prm_g[gid] = make_float4(c, vx[n] * d2p, vy[n] * d2p, log2f(Bw));
}

// ---------------------------------------------------------------------------
// Kernel 2: materialize separable bf16 factor tables (the exp2 work, computed
// ONCE per distinct (b,coord,k) instead of 16x redundantly per tile):
//   A[b][h][k] = bf16(exp2(c_k*(y_h-vy_k)^2 + log2Bw_k))   axis 0
//   B[b][w][k] = bf16(exp2(c_k*(x_w-vx_k)^2))              axis 1
// Bit-identical math to the verified fused kernel's fragment generation.
// Grid 1024 blocks: blockIdx = axis*512 + b*256 + coord.
// ---------------------------------------------------------------------------
__global__ __launch_bounds__(256) void table_kernel(
    const float4* __restrict__ prm_g, const float* __restrict__ px,
    const float* __restrict__ py,
    unsigned short* __restrict__ At, unsigned short* __restrict__ Bt)
{
    int t     = blockIdx.x;
    int axis  = t >> 9;
    int b     = (t >> 8) & 1;
    int coord = t & 255;

    float fov = px[OUT_W - 1];
    float d2p = (float)OUT_W / (2.0f * fov);
    // py[h][0] = ys[h] (row coord); px[0][w] = xs[w] (col coord)
    float v = (axis ? px[coord] : py[coord * OUT_W]) * d2p;

    const float4* prm = prm_g + b * N_ELEC;
    unsigned short* dst = (axis ? Bt : At) + (size_t)(b * 256 + coord) * N_ELEC;

    int k0 = threadIdx.x * 4;
    short4v o;
#pragma unroll
    for (int i = 0; i < 4; ++i) {
        float4 p = prm[k0 + i];
        float  d = v - (axis ? p.y : p.z);
        float  e = axis ? (p.x * d * d) : fmaf(p.x * d, d, p.w);
        o[i] = (short)f2bf(fast_exp2(e));
    }
    *(short4v*)(dst + k0) = o;   // 8B coalesced store
}

// ---------------------------------------------------------------------------
// Kernel 3: pure MFMA accumulation. Same tile/wave decomposition as the
// verified fused kernel, but fragments are direct 16B global loads from the
// L2/L3-resident tables (16 loads + 8 MFMAs per wave, ~no VALU).
// ---------------------------------------------------------------------------
__global__ __launch_bounds__(256) void mfma_kernel(
    const unsigned short* __restrict__ At,
    const unsigned short* __restrict__ Bt,
    float* __restrict__ out)
{
    __shared__ float4v red[192];

    int b    = blockIdx.x >> 8;
    int tile = blockIdx.x & 255;
    int h0   = (tile >> 4) * 16;
    int w0   = (tile & 15) * 16;
    int tid  = threadIdx.x;
    int wave = tid >> 6;
    int lane = tid & 63;
    int m    = lane & 15;   // A row / B col within tile
    int q    = lane >> 4;   // k sub-block

    const unsigned short* Ap = At + (size_t)(b * 256 + h0 + m) * N_ELEC;
    const unsigned short* Bp = Bt + (size_t)(b * 256 + w0 + m) * N_ELEC;
    int k0 = wave * 256 + q * 8;

    float4v acc = {0.0f, 0.0f, 0.0f, 0.0f};
#pragma unroll
    for (int s = 0; s < 8; ++s) {
        short8 af = *(const short8*)(Ap + k0 + s * 32);   // 16B, 16B-aligned
        short8 bf = *(const short8*)(Bp + k0 + s * 32);
        acc = __builtin_amdgcn_mfma_f32_16x16x32_bf16(af, bf, acc, 0, 0, 0);
    }

    if (wave > 0) red[(wave - 1) * 64 + lane] = acc;
    __syncthreads();
    if (wave == 0) {
        acc += red[lane];
        acc += red[64 + lane];
        acc += red[128 + lane];
        float* dst = out + (size_t)b * (OUT_H * OUT_W)
                         + (size_t)(h0 + q * 4) * OUT_W + (w0 + m);
#pragma unroll
        for (int r = 0; r < 4; ++r)
            dst[r * OUT_W] = fminf(fmaxf(acc[r] * 2.0f, 0.0f), 1.0f);
    }
}

// ---------------------------------------------------------------------------
// Fallback: the previously-verified fully-fused kernel (used if ws too small).
// ---------------------------------------------------------------------------
__global__ __launch_bounds__(256) void fused_kernel(
    const float* __restrict__ stim, const float* __restrict__ vx,
    const float* __restrict__ vy,   const float* __restrict__ M,
    const float* __restrict__ px,   const float* __restrict__ py,
    const int*   __restrict__ idx,  float* __restrict__ out)
{
    __shared__ float4  prm[N_ELEC];
    __shared__ float4v red[192];

    int b    = blockIdx.x >> 8;
    int tile = blockIdx.x & 255;
    int h0   = (tile >> 4) * 16;
    int w0   = (tile & 15) * 16;
    int tid  = threadIdx.x;
    int wave = tid >> 6;
    int lane = tid & 63;
    int m    = lane & 15;
    int q    = lane >> 4;

    float fov = px[OUT_W - 1];
    float d2p = (float)OUT_W / (2.0f * fov);

#pragma unroll
    for (int e = 0; e < 4; ++e) {
        int n = e * 256 + tid;
        int j = idx[n];
        float I    = stim[b * N_ELEC + j] * I_SCALE_C;
        float Ieff = fmaxf(I - RHEO_C, 0.0f);
        float Q    = Ieff * (PW_C * FREQ_C);
        float s    = SLOPE_C * (Q - HALF_C);
        float Bw   = 1.0f / (1.0f + __expf(-s));
        float size_base = sqrtf(I / SPREAD_C);
        float sigma_px  = fmaxf(size_base * (R2S_C / M[n]) * d2p, 1.0f);
        float c    = -LOG2E_C / (2.0f * sigma_px * sigma_px);
        prm[n] = make_float4(c, vx[n] * d2p, vy[n] * d2p, log2f(Bw));
    }
    __syncthreads();

    float yv = py[(h0 + m) * OUT_W] * d2p;
    float xv = px[w0 + m] * d2p;
    int   k0 = wave * 256;

    float4v acc = {0.0f, 0.0f, 0.0f, 0.0f};
#pragma unroll
    for (int s = 0; s < 8; ++s) {
        int kb = k0 + s * 32 + q * 8;
        short8 af, bf;
#pragma unroll
        for (int j = 0; j < 8; ++j) {
            float4 p  = prm[kb + j];
            float da  = yv - p.z;
            float ea  = fmaf(p.x * da, da, p.w);
            float db  = xv - p.y;
            float eb  = p.x * db * db;
            af[j] = (short)f2bf(fast_exp2(ea));
            bf[j] = (short)f2bf(fast_exp2(eb));
        }
        acc = __builtin_amdgcn_mfma_f32_16x16x32_bf16(af, bf, acc, 0, 0, 0);
    }

    if (wave > 0) red[(wave - 1) * 64 + lane] = acc;
    __syncthreads();
    if (wave == 0) {
        acc += red[lane];
        acc += red[64 + lane];
        acc += red[128 + lane];
        float* dst = out + (size_t)b * (OUT_H * OUT_W)
                         + (size_t)(h0 + q * 4) * OUT_W + (w0 + m);
#pragma unroll
        for (int r = 0; r < 4; ++r)
            dst[r * OUT_W] = fminf(fmaxf(acc[r] * 2.0f, 0.0f), 1.0f);
    }
}

extern "C" void kernel_launch(void* const* d_in, const int* in_sizes, int n_in,
                              void* d_out, int out_size, void* d_ws, size_t ws_size,
                              hipStream_t stream) {
    const float* stim = (const float*)d_in[0];
    const float* vx   = (const float*)d_in[1];
    const float* vy   = (const float*)d_in[2];
    const float* M    = (const float*)d_in[3];
    const float* px   = (const float*)d_in[4];
    const float* py   = (const float*)d_in[5];
    const int*   idx  = (const int*)d_in[6];
    float* out = (float*)d_out;

    const size_t TBL_BYTES = (size_t)2 * 256 * N_ELEC * sizeof(unsigned short); // 1 MB
    const size_t PRM_OFF = 0;                       // 2048 * 16B = 32 KB
    const size_t A_OFF   = 65536;
    const size_t B_OFF   = A_OFF + TBL_BYTES;
    const size_t NEED    = B_OFF + TBL_BYTES;       // ~2.06 MB

    if (d_ws != nullptr && ws_size >= NEED) {
        float4*         prm_g = (float4*)((char*)d_ws + PRM_OFF);
        unsigned short* At    = (unsigned short*)((char*)d_ws + A_OFF);
        unsigned short* Bt    = (unsigned short*)((char*)d_ws + B_OFF);
        param_kernel<<<8,    256, 0, stream>>>(stim, vx, vy, M, px, idx, prm_g);
        table_kernel<<<1024, 256, 0, stream>>>(prm_g, px, py, At, Bt);
        mfma_kernel <<<512,  256, 0, stream>>>(At, Bt, out);
    } else {
        fused_kernel<<<512, 256, 0, stream>>>(stim, vx, vy, M, px, py, idx, out);
    }
}

// Round 4
// 70.618 us; speedup vs baseline: 1.0714x; 1.0714x over previous
//
#include <hip/hip_runtime.h>
#include <math.h>

#define N_ELEC   1024
#define OUT_H    256
#define OUT_W    256
#define I_SCALE_C  8e-05f
#define RHEO_C     2.39e-05f
#define PW_C       0.00017f
#define FREQ_C     300.0f
#define SLOPE_C    19152642.5f
#define HALF_C     1.057e-07f
#define SPREAD_C   0.000675f
#define R2S_C      0.5f
#define LOG2E_C    1.4426950408889634f

typedef __attribute__((ext_vector_type(8))) short short8;
typedef __attribute__((ext_vector_type(4))) int   int4v;
typedef __attribute__((ext_vector_type(4))) float float4v;

__device__ __forceinline__ float fast_exp2(float x) {
#if __has_builtin(__builtin_amdgcn_exp2f)
    return __builtin_amdgcn_exp2f(x);
#else
    return exp2f(x);
#endif
}

// Pack two f32 -> bf16x2 with round-to-nearest-even, BIT-IDENTICAL to the
// verified scalar path ((u + 0x7fff + ((u>>16)&1)) >> 16): apply the RNE
// adjustment to both words, then extract both high halves with a single
// v_perm_b32 (bytes {uh.b3, uh.b2, ul.b3, ul.b2} == (bf(hi)<<16)|bf(lo)).
// ~5 VALU ops/pair vs ~9 for the scalar path. No exotic cvt instructions.
__device__ __forceinline__ int pk_bf16(float lo, float hi) {
    unsigned ul = __float_as_uint(lo);
    unsigned uh = __float_as_uint(hi);
    ul += 0x7fffu + ((ul >> 16) & 1u);
    uh += 0x7fffu + ((uh >> 16) & 1u);
    return (int)__builtin_amdgcn_perm(uh, ul, 0x07060302u);
}

// Fully fused, single dispatch, no workspace: one block per (batch, 16x16
// output tile). Each block recomputes the 1024 per-electrode params into LDS,
// then each of 4 waves MFMA-accumulates a K=256 electrode slice with
// register-resident bf16 fragments computed on the fly (separable Gaussian):
//   A[m][k] = exp2(c_k*(y_{h0+m}-vy_k)^2 + log2Bw_k)   (G factor, weighted)
//   B[k][n] = exp2(c_k*(x_{w0+n}-vx_k)^2)              (F factor)
__global__ __launch_bounds__(256) void fused_kernel(
    const float* __restrict__ stim, const float* __restrict__ vx,
    const float* __restrict__ vy,   const float* __restrict__ M,
    const float* __restrict__ px,   const float* __restrict__ py,
    const int*   __restrict__ idx,  float* __restrict__ out)
{
    __shared__ float4  prm[N_ELEC];   // (c, vx_px, vy_px, log2Bw)
    __shared__ float4v red[192];      // waves 1..3 partial accumulators

    int b    = blockIdx.x >> 8;
    int tile = blockIdx.x & 255;
    int h0   = (tile >> 4) * 16;
    int w0   = (tile & 15) * 16;
    int tid  = threadIdx.x;
    int wave = tid >> 6;
    int lane = tid & 63;
    int m    = lane & 15;
    int q    = lane >> 4;

    float fov = px[OUT_W - 1];
    float d2p = (float)OUT_W / (2.0f * fov);

    // ---- phase 0: per-electrode params (coalesced; 4 per thread) ----
#pragma unroll
    for (int e = 0; e < 4; ++e) {
        int n = e * 256 + tid;
        int j = idx[n];
        float I    = stim[b * N_ELEC + j] * I_SCALE_C;
        float Ieff = fmaxf(I - RHEO_C, 0.0f);
        float Q    = Ieff * (PW_C * FREQ_C);
        float s    = SLOPE_C * (Q - HALF_C);
        float Bw   = 1.0f / (1.0f + __expf(-s));
        float size_base = sqrtf(I / SPREAD_C);
        float sigma_px  = fmaxf(size_base * (R2S_C / M[n]) * d2p, 1.0f);
        float c    = -LOG2E_C / (2.0f * sigma_px * sigma_px);
        prm[n] = make_float4(c, vx[n] * d2p, vy[n] * d2p, log2f(Bw));
    }
    __syncthreads();

    // ---- phase 1: register-fragment MFMA over this wave's K-slice ----
    float yv = py[(h0 + m) * OUT_W] * d2p;   // row coord for A fragment
    float xv = px[w0 + m] * d2p;             // col coord for B fragment
    int   k0 = wave * 256;

    float4v acc = {0.0f, 0.0f, 0.0f, 0.0f};
#pragma unroll
    for (int s = 0; s < 8; ++s) {
        int kb = k0 + s * 32 + q * 8;
        int4v ai, bi;
#pragma unroll
        for (int jp = 0; jp < 4; ++jp) {
            float4 p0 = prm[kb + 2 * jp];       // 16-lane broadcast reads
            float4 p1 = prm[kb + 2 * jp + 1];
            float da0 = yv - p0.z;
            float ea0 = fmaf(p0.x * da0, da0, p0.w);
            float db0 = xv - p0.y;
            float eb0 = p0.x * db0 * db0;
            float da1 = yv - p1.z;
            float ea1 = fmaf(p1.x * da1, da1, p1.w);
            float db1 = xv - p1.y;
            float eb1 = p1.x * db1 * db1;
            ai[jp] = pk_bf16(fast_exp2(ea0), fast_exp2(ea1));
            bi[jp] = pk_bf16(fast_exp2(eb0), fast_exp2(eb1));
        }
        short8 af = __builtin_bit_cast(short8, ai);
        short8 bf = __builtin_bit_cast(short8, bi);
        acc = __builtin_amdgcn_mfma_f32_16x16x32_bf16(af, bf, acc, 0, 0, 0);
    }

    // ---- phase 2: cross-wave K-reduce + store ----
    if (wave > 0) red[(wave - 1) * 64 + lane] = acc;
    __syncthreads();
    if (wave == 0) {
        acc += red[lane];
        acc += red[64 + lane];
        acc += red[128 + lane];
        float* dst = out + (size_t)b * (OUT_H * OUT_W)
                         + (size_t)(h0 + q * 4) * OUT_W + (w0 + m);
#pragma unroll
        for (int r = 0; r < 4; ++r)
            dst[r * OUT_W] = fminf(fmaxf(acc[r] * 2.0f, 0.0f), 1.0f);
    }
}

extern "C" void kernel_launch(void* const* d_in, const int* in_sizes, int n_in,
                              void* d_out, int out_size, void* d_ws, size_t ws_size,
                              hipStream_t stream) {
    const float* stim = (const float*)d_in[0];
    const float* vx   = (const float*)d_in[1];
    const float* vy   = (const float*)d_in[2];
    const float* M    = (const float*)d_in[3];
    const float* px   = (const float*)d_in[4];
    const float* py   = (const float*)d_in[5];
    const int*   idx  = (const int*)d_in[6];
    float* out = (float*)d_out;

    // Single dispatch, no workspace: dur_us is dominated by a fixed harness
    // floor (256 MiB ws re-poison fill ~40 us + launch/restore gaps); every
    // extra dispatch costs ~2-4 us of gap, so everything stays fused.
    fused_kernel<<<512, 256, 0, stream>>>(stim, vx, vy, M, px, py, idx, out);
}